// Round 1
// baseline (58479.327 us; speedup 1.0000x reference)
//
#include <hip/hip_runtime.h>

#define T_DIM 1024
#define B_DIM 128
#define I_DIM 512
#define H_DIM 1024
#define O_DIM 512
#define TC 64
#define NCHUNK (T_DIM / TC)

typedef _Float16 half8 __attribute__((ext_vector_type(8)));
typedef _Float16 half4v __attribute__((ext_vector_type(4)));
typedef float floatx4 __attribute__((ext_vector_type(4)));

__device__ __forceinline__ void gload_lds16(const void* g, void* l) {
  __builtin_amdgcn_global_load_lds(
      (const __attribute__((address_space(1))) void*)g,
      (__attribute__((address_space(3))) void*)l, 16, 0, 0);
}

__device__ __forceinline__ float sigmoidf_(float x) {
  return 1.f / (1.f + __expf(-x));
}
__device__ __forceinline__ float tanhf_(float x) {
  float e = __expf(fminf(-2.f * x, 60.f));
  return (1.f - e) / (1.f + e);
}

// ---------------- converts ----------------
__global__ __launch_bounds__(256) void k_cvt(const float* __restrict__ s,
                                             _Float16* __restrict__ d, int n4) {
  int i = blockIdx.x * 256 + threadIdx.x;
  if (i < n4) {
    float4 v = ((const float4*)s)[i];
    half4v h = {(_Float16)v.x, (_Float16)v.y, (_Float16)v.z, (_Float16)v.w};
    ((half4v*)d)[i] = h;
  }
}

// x:(B,T,I) fp32 -> x16:(TC*B, I) fp16 rows (tl*128+b)
__global__ __launch_bounds__(256) void k_cvt_x(const float* __restrict__ x,
                                               _Float16* __restrict__ x16, int t0) {
  int i = blockIdx.x * 256 + threadIdx.x;  // per float4
  int i4 = i & 127;
  int row = i >> 7;           // 0..TC*128-1
  int b = row & 127, tl = row >> 7;
  float4 v = ((const float4*)(x + ((size_t)b * T_DIM + t0 + tl) * I_DIM))[i4];
  half4v h = {(_Float16)v.x, (_Float16)v.y, (_Float16)v.z, (_Float16)v.w};
  ((half4v*)(x16 + (size_t)row * I_DIM))[i4] = h;
}

__global__ __launch_bounds__(256) void build_bcat(const float* __restrict__ a,
                                                  const float* __restrict__ b,
                                                  const float* __restrict__ c,
                                                  const float* __restrict__ d,
                                                  float* __restrict__ o) {
  int i = blockIdx.x * 256 + threadIdx.x;
  if (i < 4096) {
    const float* p = (i < 1024) ? a : (i < 2048) ? b : (i < 3072) ? c : d;
    o[i] = p[i & 1023];
  }
}

// ---------------- GEMM: C = A[M][K] * B[N][K]^T + bias ----------------
// MODE 0: fp16 out row-major [M][N].  MODE 1: fp32 out scattered to (b,t,o).
template <int MODE>
__global__ __launch_bounds__(256) void gemm_f16(
    const _Float16* __restrict__ A, const _Float16* __restrict__ B,
    const float* __restrict__ bias, _Float16* __restrict__ C16,
    float* __restrict__ C32, int M, int N, int K, int t0) {
  __shared__ __align__(16) _Float16 As[128 * 64];
  __shared__ __align__(16) _Float16 Bs[128 * 64];
  const int tid = threadIdx.x, lane = tid & 63, wv = tid >> 6;
  const int wm = wv >> 1, wn = wv & 1;
  const int lj = lane & 15, lk = lane >> 4;
  const size_t rowA0 = (size_t)blockIdx.y * 128, colB0 = (size_t)blockIdx.x * 128;
  floatx4 acc[4][4] = {};
  for (int kb = 0; kb < K; kb += 64) {
    __syncthreads();
#pragma unroll
    for (int i = 0; i < 4; ++i) {
      int q = i * 256 + tid;
      int r = q >> 3, c = q & 7;
      gload_lds16(A + (rowA0 + r) * (size_t)K + kb + c * 8, As + (size_t)(i * 4 + wv) * 512);
    }
#pragma unroll
    for (int i = 0; i < 4; ++i) {
      int q = i * 256 + tid;
      int r = q >> 3, c = q & 7;
      gload_lds16(B + (colB0 + r) * (size_t)K + kb + c * 8, Bs + (size_t)(i * 4 + wv) * 512);
    }
    __syncthreads();
#pragma unroll
    for (int ks = 0; ks < 2; ++ks) {
      half8 af[4], bf[4];
#pragma unroll
      for (int am = 0; am < 4; ++am)
        af[am] = *(const half8*)(As + (wm * 64 + am * 16 + lj) * 64 + ks * 32 + lk * 8);
#pragma unroll
      for (int bn = 0; bn < 4; ++bn)
        bf[bn] = *(const half8*)(Bs + (wn * 64 + bn * 16 + lj) * 64 + ks * 32 + lk * 8);
#pragma unroll
      for (int am = 0; am < 4; ++am)
#pragma unroll
        for (int bn = 0; bn < 4; ++bn)
          acc[am][bn] = __builtin_amdgcn_mfma_f32_16x16x32_f16(af[am], bf[bn], acc[am][bn], 0, 0, 0);
    }
  }
#pragma unroll
  for (int am = 0; am < 4; ++am)
#pragma unroll
    for (int bn = 0; bn < 4; ++bn)
#pragma unroll
      for (int rr = 0; rr < 4; ++rr) {
        size_t grow = rowA0 + wm * 64 + am * 16 + lk * 4 + rr;
        size_t gcol = colB0 + wn * 64 + bn * 16 + lj;
        float v = acc[am][bn][rr] + bias[gcol];
        if constexpr (MODE == 0) {
          C16[grow * (size_t)N + gcol] = (_Float16)v;
        } else {
          size_t tl = grow >> 7, b = grow & 127;
          C32[b * (size_t)(T_DIM * O_DIM) + (t0 + tl) * (size_t)O_DIM + gcol] = v;
        }
      }
}

// ---------------- GRU scan over one T-chunk ----------------
// grid 256 = 8 bgroups(16 rows) x 32 jslices(32 cols); block 384 = 6 waves:
// wave wv: gate g=wv%3 (0=r,1=z,2=n), j-half jh=wv/3.
__global__ __launch_bounds__(384) void scan_kernel(
    const _Float16* __restrict__ rznx,   // [TC][128][4096]
    const _Float16* __restrict__ Whcat,  // [3][1024][1024]
    const float* __restrict__ bhr, const float* __restrict__ bhz,
    const float* __restrict__ bhn,
    _Float16* __restrict__ h16,  // [2][128][1024]
    float* __restrict__ h32,     // [128][1024]
    _Float16* __restrict__ hs16, // [TC][128][1024]
    int* __restrict__ bar, int chunk) {
  __shared__ __align__(16) _Float16 hlds[16 * 1024];
  __shared__ float exch[2][2][16 * 17];
  const int tid = threadIdx.x, lane = tid & 63, wv = tid >> 6;
  const int g = wv % 3, jh = wv / 3;
  const int bg = blockIdx.x >> 5, js = blockIdx.x & 31;
  const int b0 = bg * 16;
  const int jbase = js * 32 + jh * 16;
  const int lj = lane & 15, lk = lane >> 4;
  const int jcol = jbase + lj;

  // W fragments resident in VGPRs for the whole chunk
  half8 wf[32];
  {
    const _Float16* wb = Whcat + ((size_t)g * 1024 + jcol) * 1024 + lk * 8;
#pragma unroll
    for (int ks = 0; ks < 32; ++ks) wf[ks] = *(const half8*)(wb + ks * 32);
  }
  const float* bh = (g == 0) ? bhr : (g == 1) ? bhz : bhn;
  const float biasg = bh[jcol];
  float hown[4];
  if (g == 1) {
#pragma unroll
    for (int r = 0; r < 4; ++r) hown[r] = h32[(size_t)(b0 + lk * 4 + r) * 1024 + jcol];
  }
  int* cnt = bar + bg * 2;
  int* gen = bar + bg * 2 + 1;
  int cur = 0;
  for (int t = 0; t < TC; ++t) {
    {  // stage h16[cur] b-slice into LDS, XOR-swizzled 16B chunks
      const _Float16* hsrc = h16 + (size_t)cur * (128 * 1024) + (size_t)b0 * 1024;
#pragma unroll
      for (int i = 0; i < 6; ++i) {
        int q = tid + i * 384;
        if (q < 2048) {
          int b = q >> 7, c = q & 127;
          uint4 v = *(const uint4*)(hsrc + b * 1024 + c * 8);
          *(uint4*)((char*)hlds + b * 2048 + ((c ^ (b & 7)) * 16)) = v;
        }
      }
    }
    __syncthreads();
    floatx4 acc = {0.f, 0.f, 0.f, 0.f};
#pragma unroll
    for (int ks = 0; ks < 32; ++ks) {
      int c = ks * 4 + lk;
      int b = lj;
      half8 af = *(const half8*)((const char*)hlds + b * 2048 + ((c ^ (b & 7)) * 16));
      acc = __builtin_amdgcn_mfma_f32_16x16x32_f16(af, wf[ks], acc, 0, 0, 0);
    }
    const _Float16* xg = rznx + ((size_t)t * 128 + b0) * 4096 + g * 1024 + jcol;
    float xv[4];
#pragma unroll
    for (int r = 0; r < 4; ++r) xv[r] = (float)xg[(size_t)(lk * 4 + r) * 4096];
    float zv[4] = {0.f, 0.f, 0.f, 0.f};
    if (g == 0) {
#pragma unroll
      for (int r = 0; r < 4; ++r)
        exch[jh][0][(lk * 4 + r) * 17 + lj] = sigmoidf_(acc[r] + biasg + xv[r]);
    } else if (g == 2) {
#pragma unroll
      for (int r = 0; r < 4; ++r)
        exch[jh][1][(lk * 4 + r) * 17 + lj] = acc[r] + biasg;
    } else {
#pragma unroll
      for (int r = 0; r < 4; ++r) zv[r] = sigmoidf_(acc[r] + biasg + xv[r]);
    }
    __syncthreads();
    if (g == 1) {
#pragma unroll
      for (int r = 0; r < 4; ++r) {
        float rr = exch[jh][0][(lk * 4 + r) * 17 + lj];
        float np = exch[jh][1][(lk * 4 + r) * 17 + lj];
        float nx = (float)rznx[((size_t)t * 128 + b0 + lk * 4 + r) * 4096 + 2048 + jcol];
        float n = tanhf_(nx + rr * np);
        float hn = (1.f - zv[r]) * n + zv[r] * hown[r];
        hown[r] = hn;
        _Float16 hv = (_Float16)hn;
        h16[(size_t)(cur ^ 1) * (128 * 1024) + (size_t)(b0 + lk * 4 + r) * 1024 + jcol] = hv;
        hs16[((size_t)t * 128 + b0 + lk * 4 + r) * 1024 + jcol] = hv;
      }
      __threadfence();
    }
    __syncthreads();
    if (tid == 0) {
      const int target = chunk * TC + t + 1;
      int old = atomicAdd(cnt, 1);
      if (old == 31) {
        __hip_atomic_store(cnt, 0, __ATOMIC_RELAXED, __HIP_MEMORY_SCOPE_AGENT);
        __threadfence();
        atomicAdd(gen, 1);
      } else {
        int spin = 0;
        while (__hip_atomic_load(gen, __ATOMIC_ACQUIRE, __HIP_MEMORY_SCOPE_AGENT) < target) {
          __builtin_amdgcn_s_sleep(1);
          if (++spin > (1 << 16)) break;  // safety valve vs hang
        }
      }
    }
    __syncthreads();
    __threadfence();  // invalidate stale cached h16 lines before next stage
    cur ^= 1;
  }
  if (g == 1) {
#pragma unroll
    for (int r = 0; r < 4; ++r) h32[(size_t)(b0 + lk * 4 + r) * 1024 + jcol] = hown[r];
  }
}

// ---------------- LayerNorm(hs + skip) -> fp16 ----------------
__global__ __launch_bounds__(256) void ln_kernel(
    const _Float16* __restrict__ hs, const _Float16* __restrict__ rz,
    const float* __restrict__ gamma, const float* __restrict__ beta,
    _Float16* __restrict__ outp) {
  const int row = blockIdx.x, tid = threadIdx.x;
  const int lane = tid & 63, wv = tid >> 6;
  half4v hv = *(const half4v*)(hs + (size_t)row * 1024 + tid * 4);
  half4v sv = *(const half4v*)(rz + (size_t)row * 4096 + 3072 + tid * 4);
  float v[4];
  float s = 0.f, s2 = 0.f;
#pragma unroll
  for (int j = 0; j < 4; ++j) {
    v[j] = (float)hv[j] + (float)sv[j];
    s += v[j];
    s2 += v[j] * v[j];
  }
#pragma unroll
  for (int o = 32; o > 0; o >>= 1) {
    s += __shfl_xor(s, o, 64);
    s2 += __shfl_xor(s2, o, 64);
  }
  __shared__ float ps[4][2];
  if (lane == 0) { ps[wv][0] = s; ps[wv][1] = s2; }
  __syncthreads();
  s = ps[0][0] + ps[1][0] + ps[2][0] + ps[3][0];
  s2 = ps[0][1] + ps[1][1] + ps[2][1] + ps[3][1];
  const float mu = s * (1.f / 1024.f);
  const float var = s2 * (1.f / 1024.f) - mu * mu;
  const float rstd = rsqrtf(var + 1e-5f);
  half4v ov;
#pragma unroll
  for (int j = 0; j < 4; ++j)
    ov[j] = (_Float16)((v[j] - mu) * rstd * gamma[tid * 4 + j] + beta[tid * 4 + j]);
  *(half4v*)(outp + (size_t)row * 1024 + tid * 4) = ov;
}

// ---------------- host ----------------
extern "C" void kernel_launch(void* const* d_in, const int* in_sizes, int n_in,
                              void* d_out, int out_size, void* d_ws, size_t ws_size,
                              hipStream_t stream) {
  const float* x     = (const float*)d_in[0];
  const float* Wir   = (const float*)d_in[1];
  const float* bir   = (const float*)d_in[2];
  const float* Whr   = (const float*)d_in[3];
  const float* bhr   = (const float*)d_in[4];
  const float* Wiz   = (const float*)d_in[5];
  const float* biz   = (const float*)d_in[6];
  const float* Whz   = (const float*)d_in[7];
  const float* bhz   = (const float*)d_in[8];
  const float* Win   = (const float*)d_in[9];
  const float* bin_  = (const float*)d_in[10];
  const float* Whn   = (const float*)d_in[11];
  const float* bhn   = (const float*)d_in[12];
  const float* Wskip = (const float*)d_in[13];
  const float* bskip = (const float*)d_in[14];
  const float* gamma = (const float*)d_in[15];
  const float* beta  = (const float*)d_in[16];
  const float* Wout  = (const float*)d_in[17];
  const float* bout  = (const float*)d_in[18];
  float* out = (float*)d_out;

  char* ws = (char*)d_ws;
  size_t off = 0;
  auto alloc = [&](size_t bytes) -> char* {
    char* p = ws + off;
    off += (bytes + 255) & ~(size_t)255;
    return p;
  };
  _Float16* x16    = (_Float16*)alloc((size_t)TC * 128 * 512 * 2);
  _Float16* Wcat   = (_Float16*)alloc((size_t)4096 * 512 * 2);
  _Float16* Whcat  = (_Float16*)alloc((size_t)3072 * 1024 * 2);
  _Float16* Wout16 = (_Float16*)alloc((size_t)512 * 1024 * 2);
  float*    bcat   = (float*)alloc(4096 * 4);
  _Float16* rznx   = (_Float16*)alloc((size_t)TC * 128 * 4096 * 2);
  _Float16* h16    = (_Float16*)alloc((size_t)2 * 128 * 1024 * 2);
  float*    h32    = (float*)alloc((size_t)128 * 1024 * 4);
  _Float16* hs16   = (_Float16*)alloc((size_t)TC * 128 * 1024 * 2);
  _Float16* normed = (_Float16*)alloc((size_t)TC * 128 * 1024 * 2);
  int*      bar    = (int*)alloc(256);

  k_cvt<<<512, 256, 0, stream>>>(Wir, Wcat + 0 * 524288, 131072);
  k_cvt<<<512, 256, 0, stream>>>(Wiz, Wcat + 1 * 524288, 131072);
  k_cvt<<<512, 256, 0, stream>>>(Win, Wcat + 2 * 524288, 131072);
  k_cvt<<<512, 256, 0, stream>>>(Wskip, Wcat + 3 * 524288, 131072);
  k_cvt<<<1024, 256, 0, stream>>>(Whr, Whcat + 0 * 1048576, 262144);
  k_cvt<<<1024, 256, 0, stream>>>(Whz, Whcat + 1 * 1048576, 262144);
  k_cvt<<<1024, 256, 0, stream>>>(Whn, Whcat + 2 * 1048576, 262144);
  k_cvt<<<512, 256, 0, stream>>>(Wout, Wout16, 131072);
  build_bcat<<<16, 256, 0, stream>>>(bir, biz, bin_, bskip, bcat);
  hipMemsetAsync(h16, 0, (size_t)2 * 128 * 1024 * 2, stream);
  hipMemsetAsync(h32, 0, (size_t)128 * 1024 * 4, stream);
  hipMemsetAsync(bar, 0, 256, stream);

  for (int c = 0; c < NCHUNK; ++c) {
    int t0 = c * TC;
    k_cvt_x<<<(TC * 128 * 512 / 4) / 256, 256, 0, stream>>>(x, x16, t0);
    gemm_f16<0><<<dim3(4096 / 128, TC * 128 / 128), 256, 0, stream>>>(
        x16, Wcat, bcat, rznx, nullptr, TC * 128, 4096, 512, 0);
    scan_kernel<<<256, 384, 0, stream>>>(rznx, Whcat, bhr, bhz, bhn, h16, h32, hs16, bar, c);
    ln_kernel<<<TC * 128, 256, 0, stream>>>(hs16, rznx, gamma, beta, normed);
    gemm_f16<1><<<dim3(512 / 128, TC * 128 / 128), 256, 0, stream>>>(
        normed, Wout16, bout, nullptr, out, TC * 128, 512, 1024, t0);
  }
}

// Round 2
// 40378.467 us; speedup vs baseline: 1.4483x; 1.4483x over previous
//
#include <hip/hip_runtime.h>

#define T_DIM 1024
#define B_DIM 128
#define I_DIM 512
#define H_DIM 1024
#define O_DIM 512
#define TC 64
#define NCHUNK (T_DIM / TC)

typedef _Float16 half8 __attribute__((ext_vector_type(8)));
typedef _Float16 half4v __attribute__((ext_vector_type(4)));
typedef float floatx4 __attribute__((ext_vector_type(4)));

__device__ __forceinline__ void gload_lds16(const void* g, void* l) {
  __builtin_amdgcn_global_load_lds(
      (const __attribute__((address_space(1))) void*)g,
      (__attribute__((address_space(3))) void*)l, 16, 0, 0);
}

__device__ __forceinline__ float sigmoidf_(float x) {
  return 1.f / (1.f + __expf(-x));
}
__device__ __forceinline__ float tanhf_(float x) {
  float e = __expf(fminf(-2.f * x, 60.f));
  return (1.f - e) / (1.f + e);
}

// ---------------- converts ----------------
__global__ __launch_bounds__(256) void k_cvt(const float* __restrict__ s,
                                             _Float16* __restrict__ d, int n4) {
  int i = blockIdx.x * 256 + threadIdx.x;
  if (i < n4) {
    float4 v = ((const float4*)s)[i];
    half4v h = {(_Float16)v.x, (_Float16)v.y, (_Float16)v.z, (_Float16)v.w};
    ((half4v*)d)[i] = h;
  }
}

// x:(B,T,I) fp32 -> x16:(TC*B, I) fp16 rows (tl*128+b)
__global__ __launch_bounds__(256) void k_cvt_x(const float* __restrict__ x,
                                               _Float16* __restrict__ x16, int t0) {
  int i = blockIdx.x * 256 + threadIdx.x;  // per float4
  int i4 = i & 127;
  int row = i >> 7;           // 0..TC*128-1
  int b = row & 127, tl = row >> 7;
  float4 v = ((const float4*)(x + ((size_t)b * T_DIM + t0 + tl) * I_DIM))[i4];
  half4v h = {(_Float16)v.x, (_Float16)v.y, (_Float16)v.z, (_Float16)v.w};
  ((half4v*)(x16 + (size_t)row * I_DIM))[i4] = h;
}

__global__ __launch_bounds__(256) void build_bcat(const float* __restrict__ a,
                                                  const float* __restrict__ b,
                                                  const float* __restrict__ c,
                                                  const float* __restrict__ d,
                                                  float* __restrict__ o) {
  int i = blockIdx.x * 256 + threadIdx.x;
  if (i < 4096) {
    const float* p = (i < 1024) ? a : (i < 2048) ? b : (i < 3072) ? c : d;
    o[i] = p[i & 1023];
  }
}

// ---------------- GEMM: C = A[M][K] * B[N][K]^T + bias ----------------
// MODE 0: fp16 out row-major [M][N].  MODE 1: fp32 out scattered to (b,t,o).
template <int MODE>
__global__ __launch_bounds__(256) void gemm_f16(
    const _Float16* __restrict__ A, const _Float16* __restrict__ B,
    const float* __restrict__ bias, _Float16* __restrict__ C16,
    float* __restrict__ C32, int M, int N, int K, int t0) {
  __shared__ __align__(16) _Float16 As[128 * 64];
  __shared__ __align__(16) _Float16 Bs[128 * 64];
  const int tid = threadIdx.x, lane = tid & 63, wv = tid >> 6;
  const int wm = wv >> 1, wn = wv & 1;
  const int lj = lane & 15, lk = lane >> 4;
  const size_t rowA0 = (size_t)blockIdx.y * 128, colB0 = (size_t)blockIdx.x * 128;
  floatx4 acc[4][4] = {};
  for (int kb = 0; kb < K; kb += 64) {
    __syncthreads();
#pragma unroll
    for (int i = 0; i < 4; ++i) {
      int q = i * 256 + tid;
      int r = q >> 3, c = q & 7;
      gload_lds16(A + (rowA0 + r) * (size_t)K + kb + c * 8, As + (size_t)(i * 4 + wv) * 512);
    }
#pragma unroll
    for (int i = 0; i < 4; ++i) {
      int q = i * 256 + tid;
      int r = q >> 3, c = q & 7;
      gload_lds16(B + (colB0 + r) * (size_t)K + kb + c * 8, Bs + (size_t)(i * 4 + wv) * 512);
    }
    __syncthreads();
#pragma unroll
    for (int ks = 0; ks < 2; ++ks) {
      half8 af[4], bf[4];
#pragma unroll
      for (int am = 0; am < 4; ++am)
        af[am] = *(const half8*)(As + (wm * 64 + am * 16 + lj) * 64 + ks * 32 + lk * 8);
#pragma unroll
      for (int bn = 0; bn < 4; ++bn)
        bf[bn] = *(const half8*)(Bs + (wn * 64 + bn * 16 + lj) * 64 + ks * 32 + lk * 8);
#pragma unroll
      for (int am = 0; am < 4; ++am)
#pragma unroll
        for (int bn = 0; bn < 4; ++bn)
          acc[am][bn] = __builtin_amdgcn_mfma_f32_16x16x32_f16(af[am], bf[bn], acc[am][bn], 0, 0, 0);
    }
  }
#pragma unroll
  for (int am = 0; am < 4; ++am)
#pragma unroll
    for (int bn = 0; bn < 4; ++bn)
#pragma unroll
      for (int rr = 0; rr < 4; ++rr) {
        size_t grow = rowA0 + wm * 64 + am * 16 + lk * 4 + rr;
        size_t gcol = colB0 + wn * 64 + bn * 16 + lj;
        float v = acc[am][bn][rr] + bias[gcol];
        if constexpr (MODE == 0) {
          C16[grow * (size_t)N + gcol] = (_Float16)v;
        } else {
          size_t tl = grow >> 7, b = grow & 127;
          C32[b * (size_t)(T_DIM * O_DIM) + (t0 + tl) * (size_t)O_DIM + gcol] = v;
        }
      }
}

// ---------------- GRU scan over one T-chunk ----------------
// grid 256 = 8 bgroups(16 rows) x 32 jslices(32 cols); block 384 = 6 waves:
// wave wv: gate g=wv%3 (0=r,1=z,2=n), j-half jh=wv/3.
// bg = blockIdx.x & 7 -> a bgroup's 32 blocks land on the SAME XCD under
// round-robin dispatch (h16 producer/consumer stays L2-local).
// Barrier: one PRIVATE 256B region per bgroup, single monotonic counter.
__global__ __launch_bounds__(384) void scan_kernel(
    const _Float16* __restrict__ rznx,   // [TC][128][4096]
    const _Float16* __restrict__ Whcat,  // [3][1024][1024]
    const float* __restrict__ bhr, const float* __restrict__ bhz,
    const float* __restrict__ bhn,
    _Float16* __restrict__ h16,  // [2][128][1024]
    float* __restrict__ h32,     // [128][1024]
    _Float16* __restrict__ hs16, // [TC][128][1024]
    int* __restrict__ bar, int chunk) {
  __shared__ __align__(16) _Float16 hlds[16 * 1024];
  __shared__ float exch[2][2][16 * 17];
  const int tid = threadIdx.x, lane = tid & 63, wv = tid >> 6;
  const int g = wv % 3, jh = wv / 3;
  const int bg = blockIdx.x & 7, js = blockIdx.x >> 3;
  const int b0 = bg * 16;
  const int jbase = js * 32 + jh * 16;
  const int lj = lane & 15, lk = lane >> 4;
  const int jcol = jbase + lj;

  // W fragments resident in VGPRs for the whole chunk
  half8 wf[32];
  {
    const _Float16* wb = Whcat + ((size_t)g * 1024 + jcol) * 1024 + lk * 8;
#pragma unroll
    for (int ks = 0; ks < 32; ++ks) wf[ks] = *(const half8*)(wb + ks * 32);
  }
  const float* bh = (g == 0) ? bhr : (g == 1) ? bhz : bhn;
  const float biasg = bh[jcol];
  float hown[4];
  if (g == 1) {
#pragma unroll
    for (int r = 0; r < 4; ++r) hown[r] = h32[(size_t)(b0 + lk * 4 + r) * 1024 + jcol];
  }
  int* cnt = bar + bg * 64;  // 256B-padded private line per bgroup
  int cur = 0;
  for (int t = 0; t < TC; ++t) {
    {  // stage h16[cur] b-slice into LDS, XOR-swizzled 16B chunks
      const _Float16* hsrc = h16 + (size_t)cur * (128 * 1024) + (size_t)b0 * 1024;
#pragma unroll
      for (int i = 0; i < 6; ++i) {
        int q = tid + i * 384;
        if (q < 2048) {
          int b = q >> 7, c = q & 127;
          uint4 v = *(const uint4*)(hsrc + b * 1024 + c * 8);
          *(uint4*)((char*)hlds + b * 2048 + ((c ^ (b & 7)) * 16)) = v;
        }
      }
    }
    __syncthreads();
    floatx4 acc = {0.f, 0.f, 0.f, 0.f};
#pragma unroll
    for (int ks = 0; ks < 32; ++ks) {
      int c = ks * 4 + lk;
      int b = lj;
      half8 af = *(const half8*)((const char*)hlds + b * 2048 + ((c ^ (b & 7)) * 16));
      acc = __builtin_amdgcn_mfma_f32_16x16x32_f16(af, wf[ks], acc, 0, 0, 0);
    }
    const _Float16* xg = rznx + ((size_t)t * 128 + b0) * 4096 + g * 1024 + jcol;
    float xv[4];
#pragma unroll
    for (int r = 0; r < 4; ++r) xv[r] = (float)xg[(size_t)(lk * 4 + r) * 4096];
    float zv[4] = {0.f, 0.f, 0.f, 0.f};
    if (g == 0) {
#pragma unroll
      for (int r = 0; r < 4; ++r)
        exch[jh][0][(lk * 4 + r) * 17 + lj] = sigmoidf_(acc[r] + biasg + xv[r]);
    } else if (g == 2) {
#pragma unroll
      for (int r = 0; r < 4; ++r)
        exch[jh][1][(lk * 4 + r) * 17 + lj] = acc[r] + biasg;
    } else {
#pragma unroll
      for (int r = 0; r < 4; ++r) zv[r] = sigmoidf_(acc[r] + biasg + xv[r]);
    }
    __syncthreads();
    if (g == 1) {
#pragma unroll
      for (int r = 0; r < 4; ++r) {
        float rr = exch[jh][0][(lk * 4 + r) * 17 + lj];
        float np = exch[jh][1][(lk * 4 + r) * 17 + lj];
        float nx = (float)rznx[((size_t)t * 128 + b0 + lk * 4 + r) * 4096 + 2048 + jcol];
        float n = tanhf_(nx + rr * np);
        float hn = (1.f - zv[r]) * n + zv[r] * hown[r];
        hown[r] = hn;
        _Float16 hv = (_Float16)hn;
        h16[(size_t)(cur ^ 1) * (128 * 1024) + (size_t)(b0 + lk * 4 + r) * 1024 + jcol] = hv;
        hs16[((size_t)t * 128 + b0 + lk * 4 + r) * 1024 + jcol] = hv;
      }
      __threadfence();  // release: h-writes device-visible before arrival
    }
    __syncthreads();
    if (tid == 0) {
      const int target = 32 * (chunk * TC + t + 1);
      atomicAdd(cnt, 1);
      int spin = 0;
      while (__hip_atomic_load(cnt, __ATOMIC_RELAXED, __HIP_MEMORY_SCOPE_AGENT) < target) {
        __builtin_amdgcn_s_sleep(1);
        if (++spin > (1 << 16)) break;  // safety valve vs hang
      }
    }
    __syncthreads();
    __threadfence();  // acquire: invalidate stale cached h16 lines before next stage
    cur ^= 1;
  }
  if (g == 1) {
#pragma unroll
    for (int r = 0; r < 4; ++r) h32[(size_t)(b0 + lk * 4 + r) * 1024 + jcol] = hown[r];
  }
}

// ---------------- LayerNorm(hs + skip) -> fp16 ----------------
__global__ __launch_bounds__(256) void ln_kernel(
    const _Float16* __restrict__ hs, const _Float16* __restrict__ rz,
    const float* __restrict__ gamma, const float* __restrict__ beta,
    _Float16* __restrict__ outp) {
  const int row = blockIdx.x, tid = threadIdx.x;
  const int lane = tid & 63, wv = tid >> 6;
  half4v hv = *(const half4v*)(hs + (size_t)row * 1024 + tid * 4);
  half4v sv = *(const half4v*)(rz + (size_t)row * 4096 + 3072 + tid * 4);
  float v[4];
  float s = 0.f, s2 = 0.f;
#pragma unroll
  for (int j = 0; j < 4; ++j) {
    v[j] = (float)hv[j] + (float)sv[j];
    s += v[j];
    s2 += v[j] * v[j];
  }
#pragma unroll
  for (int o = 32; o > 0; o >>= 1) {
    s += __shfl_xor(s, o, 64);
    s2 += __shfl_xor(s2, o, 64);
  }
  __shared__ float ps[4][2];
  if (lane == 0) { ps[wv][0] = s; ps[wv][1] = s2; }
  __syncthreads();
  s = ps[0][0] + ps[1][0] + ps[2][0] + ps[3][0];
  s2 = ps[0][1] + ps[1][1] + ps[2][1] + ps[3][1];
  const float mu = s * (1.f / 1024.f);
  const float var = s2 * (1.f / 1024.f) - mu * mu;
  const float rstd = rsqrtf(var + 1e-5f);
  half4v ov;
#pragma unroll
  for (int j = 0; j < 4; ++j)
    ov[j] = (_Float16)((v[j] - mu) * rstd * gamma[tid * 4 + j] + beta[tid * 4 + j]);
  *(half4v*)(outp + (size_t)row * 1024 + tid * 4) = ov;
}

// ---------------- host ----------------
extern "C" void kernel_launch(void* const* d_in, const int* in_sizes, int n_in,
                              void* d_out, int out_size, void* d_ws, size_t ws_size,
                              hipStream_t stream) {
  const float* x     = (const float*)d_in[0];
  const float* Wir   = (const float*)d_in[1];
  const float* bir   = (const float*)d_in[2];
  const float* Whr   = (const float*)d_in[3];
  const float* bhr   = (const float*)d_in[4];
  const float* Wiz   = (const float*)d_in[5];
  const float* biz   = (const float*)d_in[6];
  const float* Whz   = (const float*)d_in[7];
  const float* bhz   = (const float*)d_in[8];
  const float* Win   = (const float*)d_in[9];
  const float* bin_  = (const float*)d_in[10];
  const float* Whn   = (const float*)d_in[11];
  const float* bhn   = (const float*)d_in[12];
  const float* Wskip = (const float*)d_in[13];
  const float* bskip = (const float*)d_in[14];
  const float* gamma = (const float*)d_in[15];
  const float* beta  = (const float*)d_in[16];
  const float* Wout  = (const float*)d_in[17];
  const float* bout  = (const float*)d_in[18];
  float* out = (float*)d_out;

  char* ws = (char*)d_ws;
  size_t off = 0;
  auto alloc = [&](size_t bytes) -> char* {
    char* p = ws + off;
    off += (bytes + 255) & ~(size_t)255;
    return p;
  };
  _Float16* x16    = (_Float16*)alloc((size_t)TC * 128 * 512 * 2);
  _Float16* Wcat   = (_Float16*)alloc((size_t)4096 * 512 * 2);
  _Float16* Whcat  = (_Float16*)alloc((size_t)3072 * 1024 * 2);
  _Float16* Wout16 = (_Float16*)alloc((size_t)512 * 1024 * 2);
  float*    bcat   = (float*)alloc(4096 * 4);
  _Float16* rznx   = (_Float16*)alloc((size_t)TC * 128 * 4096 * 2);
  _Float16* h16    = (_Float16*)alloc((size_t)2 * 128 * 1024 * 2);
  float*    h32    = (float*)alloc((size_t)128 * 1024 * 4);
  _Float16* hs16   = (_Float16*)alloc((size_t)TC * 128 * 1024 * 2);
  _Float16* normed = (_Float16*)alloc((size_t)TC * 128 * 1024 * 2);
  int*      bar    = (int*)alloc(8 * 256);

  k_cvt<<<512, 256, 0, stream>>>(Wir, Wcat + 0 * 524288, 131072);
  k_cvt<<<512, 256, 0, stream>>>(Wiz, Wcat + 1 * 524288, 131072);
  k_cvt<<<512, 256, 0, stream>>>(Win, Wcat + 2 * 524288, 131072);
  k_cvt<<<512, 256, 0, stream>>>(Wskip, Wcat + 3 * 524288, 131072);
  k_cvt<<<1024, 256, 0, stream>>>(Whr, Whcat + 0 * 1048576, 262144);
  k_cvt<<<1024, 256, 0, stream>>>(Whz, Whcat + 1 * 1048576, 262144);
  k_cvt<<<1024, 256, 0, stream>>>(Whn, Whcat + 2 * 1048576, 262144);
  k_cvt<<<512, 256, 0, stream>>>(Wout, Wout16, 131072);
  build_bcat<<<16, 256, 0, stream>>>(bir, biz, bin_, bskip, bcat);
  hipMemsetAsync(h16, 0, (size_t)2 * 128 * 1024 * 2, stream);
  hipMemsetAsync(h32, 0, (size_t)128 * 1024 * 4, stream);
  hipMemsetAsync(bar, 0, 8 * 256, stream);

  for (int c = 0; c < NCHUNK; ++c) {
    int t0 = c * TC;
    k_cvt_x<<<(TC * 128 * 512 / 4) / 256, 256, 0, stream>>>(x, x16, t0);
    gemm_f16<0><<<dim3(4096 / 128, TC * 128 / 128), 256, 0, stream>>>(
        x16, Wcat, bcat, rznx, nullptr, TC * 128, 4096, 512, 0);
    scan_kernel<<<256, 384, 0, stream>>>(rznx, Whcat, bhr, bhz, bhn, h16, h32, hs16, bar, c);
    ln_kernel<<<TC * 128, 256, 0, stream>>>(hs16, rznx, gamma, beta, normed);
    gemm_f16<1><<<dim3(512 / 128, TC * 128 / 128), 256, 0, stream>>>(
        normed, Wout16, bout, nullptr, out, TC * 128, 512, 1024, t0);
  }
}

// Round 3
// 5329.190 us; speedup vs baseline: 10.9734x; 7.5768x over previous
//
#include <hip/hip_runtime.h>

#define T_DIM 1024
#define B_DIM 128
#define I_DIM 512
#define H_DIM 1024
#define O_DIM 512
#define TC 64
#define NCHUNK (T_DIM / TC)

typedef _Float16 half8 __attribute__((ext_vector_type(8)));
typedef _Float16 half4v __attribute__((ext_vector_type(4)));
typedef float floatx4 __attribute__((ext_vector_type(4)));
typedef unsigned int uint4v __attribute__((ext_vector_type(4)));

__device__ __forceinline__ void gload_lds16(const void* g, void* l) {
  __builtin_amdgcn_global_load_lds(
      (const __attribute__((address_space(1))) void*)g,
      (__attribute__((address_space(3))) void*)l, 16, 0, 0);
}

__device__ __forceinline__ float sigmoidf_(float x) {
  return 1.f / (1.f + __expf(-x));
}
__device__ __forceinline__ float tanhf_(float x) {
  float e = __expf(fminf(-2.f * x, 60.f));
  return (1.f - e) / (1.f + e);
}

// ---------------- converts ----------------
__global__ __launch_bounds__(256) void k_cvt(const float* __restrict__ s,
                                             _Float16* __restrict__ d, int n4) {
  int i = blockIdx.x * 256 + threadIdx.x;
  if (i < n4) {
    float4 v = ((const float4*)s)[i];
    half4v h = {(_Float16)v.x, (_Float16)v.y, (_Float16)v.z, (_Float16)v.w};
    ((half4v*)d)[i] = h;
  }
}

// x:(B,T,I) fp32 -> x16:(TC*B, I) fp16 rows (tl*128+b)
__global__ __launch_bounds__(256) void k_cvt_x(const float* __restrict__ x,
                                               _Float16* __restrict__ x16, int t0) {
  int i = blockIdx.x * 256 + threadIdx.x;  // per float4
  int i4 = i & 127;
  int row = i >> 7;           // 0..TC*128-1
  int b = row & 127, tl = row >> 7;
  float4 v = ((const float4*)(x + ((size_t)b * T_DIM + t0 + tl) * I_DIM))[i4];
  half4v h = {(_Float16)v.x, (_Float16)v.y, (_Float16)v.z, (_Float16)v.w};
  ((half4v*)(x16 + (size_t)row * I_DIM))[i4] = h;
}

__global__ __launch_bounds__(256) void build_bcat(const float* __restrict__ a,
                                                  const float* __restrict__ b,
                                                  const float* __restrict__ c,
                                                  const float* __restrict__ d,
                                                  float* __restrict__ o) {
  int i = blockIdx.x * 256 + threadIdx.x;
  if (i < 4096) {
    const float* p = (i < 1024) ? a : (i < 2048) ? b : (i < 3072) ? c : d;
    o[i] = p[i & 1023];
  }
}

// ---------------- GEMM: C = A[M][K] * B[N][K]^T + bias ----------------
// MODE 0: fp16 out row-major [M][N].  MODE 1: fp32 out scattered to (b,t,o).
template <int MODE>
__global__ __launch_bounds__(256) void gemm_f16(
    const _Float16* __restrict__ A, const _Float16* __restrict__ B,
    const float* __restrict__ bias, _Float16* __restrict__ C16,
    float* __restrict__ C32, int M, int N, int K, int t0) {
  __shared__ __align__(16) _Float16 As[128 * 64];
  __shared__ __align__(16) _Float16 Bs[128 * 64];
  const int tid = threadIdx.x, lane = tid & 63, wv = tid >> 6;
  const int wm = wv >> 1, wn = wv & 1;
  const int lj = lane & 15, lk = lane >> 4;
  const size_t rowA0 = (size_t)blockIdx.y * 128, colB0 = (size_t)blockIdx.x * 128;
  floatx4 acc[4][4] = {};
  for (int kb = 0; kb < K; kb += 64) {
    __syncthreads();
#pragma unroll
    for (int i = 0; i < 4; ++i) {
      int q = i * 256 + tid;
      int r = q >> 3, c = q & 7;
      gload_lds16(A + (rowA0 + r) * (size_t)K + kb + c * 8, As + (size_t)(i * 4 + wv) * 512);
    }
#pragma unroll
    for (int i = 0; i < 4; ++i) {
      int q = i * 256 + tid;
      int r = q >> 3, c = q & 7;
      gload_lds16(B + (colB0 + r) * (size_t)K + kb + c * 8, Bs + (size_t)(i * 4 + wv) * 512);
    }
    __syncthreads();
#pragma unroll
    for (int ks = 0; ks < 2; ++ks) {
      half8 af[4], bf[4];
#pragma unroll
      for (int am = 0; am < 4; ++am)
        af[am] = *(const half8*)(As + (wm * 64 + am * 16 + lj) * 64 + ks * 32 + lk * 8);
#pragma unroll
      for (int bn = 0; bn < 4; ++bn)
        bf[bn] = *(const half8*)(Bs + (wn * 64 + bn * 16 + lj) * 64 + ks * 32 + lk * 8);
#pragma unroll
      for (int am = 0; am < 4; ++am)
#pragma unroll
        for (int bn = 0; bn < 4; ++bn)
          acc[am][bn] = __builtin_amdgcn_mfma_f32_16x16x32_f16(af[am], bf[bn], acc[am][bn], 0, 0, 0);
    }
  }
#pragma unroll
  for (int am = 0; am < 4; ++am)
#pragma unroll
    for (int bn = 0; bn < 4; ++bn)
#pragma unroll
      for (int rr = 0; rr < 4; ++rr) {
        size_t grow = rowA0 + wm * 64 + am * 16 + lk * 4 + rr;
        size_t gcol = colB0 + wn * 64 + bn * 16 + lj;
        float v = acc[am][bn][rr] + bias[gcol];
        if constexpr (MODE == 0) {
          C16[grow * (size_t)N + gcol] = (_Float16)v;
        } else {
          size_t tl = grow >> 7, b = grow & 127;
          C32[b * (size_t)(T_DIM * O_DIM) + (t0 + tl) * (size_t)O_DIM + gcol] = v;
        }
      }
}

// ---------------- GRU scan over one T-chunk ----------------
// grid 256 = 8 bgroups(16 rows) x 32 jslices(32 cols); block 384 = 6 waves:
// wave wv: gate g=wv%3 (0=r,1=z,2=n), j-half jh=wv/3.
// NO atomics, NO __threadfence: h16 handoff is done with sc0+sc1 (fabric-
// coherent, write-through) loads/stores — valid on any XCD mapping, no L2
// flush ops. Barrier = per-block flag stores + one polling wave.
__global__ __launch_bounds__(384) void scan_kernel(
    const _Float16* __restrict__ rznx,   // [TC][128][4096]
    const _Float16* __restrict__ Whcat,  // [3][1024][1024]
    const float* __restrict__ bhr, const float* __restrict__ bhz,
    const float* __restrict__ bhn,
    _Float16* __restrict__ h16,  // [2][128][1024]  (fabric-coherent buffer)
    float* __restrict__ h32,     // [128][1024]
    _Float16* __restrict__ hs16, // [TC][128][1024]
    int* __restrict__ flags,     // [8][32] flags, each padded to 128B (32 ints)
    int chunk) {
  __shared__ __align__(16) _Float16 hlds[16 * 1024];
  __shared__ float exch[2][2][16 * 17];
  __shared__ __align__(16) _Float16 hout[16][32];
  const int tid = threadIdx.x, lane = tid & 63, wv = tid >> 6;
  const int g = wv % 3, jh = wv / 3;
  const int bg = blockIdx.x & 7, js = blockIdx.x >> 3;
  const int b0 = bg * 16;
  const int jbase = js * 32 + jh * 16;
  const int lj = lane & 15, lk = lane >> 4;
  const int jcol = jbase + lj;

  // W fragments resident in VGPRs for the whole chunk
  half8 wf[32];
  {
    const _Float16* wb = Whcat + ((size_t)g * 1024 + jcol) * 1024 + lk * 8;
#pragma unroll
    for (int ks = 0; ks < 32; ++ks) wf[ks] = *(const half8*)(wb + ks * 32);
  }
  const float* bh = (g == 0) ? bhr : (g == 1) ? bhz : bhn;
  const float biasg = bh[jcol];
  float hown[4];
  if (g == 1) {
#pragma unroll
    for (int r = 0; r < 4; ++r) hown[r] = h32[(size_t)(b0 + lk * 4 + r) * 1024 + jcol];
  }
  int cur = 0;
  for (int t = 0; t < TC; ++t) {
    const int gs = chunk * TC + t;  // global step index (monotonic)
    // ---- prefetch x-side gate inputs for THIS step (independent of h) ----
    const _Float16* xg = rznx + ((size_t)t * 128 + b0) * 4096 + g * 1024 + jcol;
    float xv[4];
#pragma unroll
    for (int r = 0; r < 4; ++r) xv[r] = (float)xg[(size_t)(lk * 4 + r) * 4096];
    float nxv[4];
    if (g == 1) {
#pragma unroll
      for (int r = 0; r < 4; ++r)
        nxv[r] = (float)rznx[((size_t)t * 128 + b0 + lk * 4 + r) * 4096 + 2048 + jcol];
    }
    // ---- stage h16[cur] (waves 0-3): fabric-coherent loads -> swizzled LDS ----
    if (tid < 256) {
      const _Float16* hsrc = h16 + (size_t)cur * (128 * 1024) + (size_t)b0 * 1024;
      uint4v vv[8];
      const char* ap[8];
#pragma unroll
      for (int i = 0; i < 8; ++i) {
        int q = tid + i * 256;  // 0..2047
        int b = q >> 7, c = q & 127;
        ap[i] = (const char*)(hsrc + b * 1024 + c * 8);
      }
#pragma unroll
      for (int i = 0; i < 8; ++i)
        asm volatile("global_load_dwordx4 %0, %1, off sc0 sc1"
                     : "=v"(vv[i]) : "v"(ap[i]));
      asm volatile("s_waitcnt vmcnt(0)" ::: "memory");
#pragma unroll
      for (int i = 0; i < 8; ++i) {
        int q = tid + i * 256;
        int b = q >> 7, c = q & 127;
        *(uint4v*)((char*)hlds + b * 2048 + ((c ^ (b & 7)) * 16)) = vv[i];
      }
    }
    __syncthreads();  // (A) h staged
    floatx4 acc = {0.f, 0.f, 0.f, 0.f};
#pragma unroll
    for (int ks = 0; ks < 32; ++ks) {
      int c = ks * 4 + lk;
      int b = lj;
      half8 af = *(const half8*)((const char*)hlds + b * 2048 + ((c ^ (b & 7)) * 16));
      acc = __builtin_amdgcn_mfma_f32_16x16x32_f16(af, wf[ks], acc, 0, 0, 0);
    }
    float zv[4] = {0.f, 0.f, 0.f, 0.f};
    if (g == 0) {
#pragma unroll
      for (int r = 0; r < 4; ++r)
        exch[jh][0][(lk * 4 + r) * 17 + lj] = sigmoidf_(acc[r] + biasg + xv[r]);
    } else if (g == 2) {
#pragma unroll
      for (int r = 0; r < 4; ++r)
        exch[jh][1][(lk * 4 + r) * 17 + lj] = acc[r] + biasg;
    } else {
#pragma unroll
      for (int r = 0; r < 4; ++r) zv[r] = sigmoidf_(acc[r] + biasg + xv[r]);
    }
    __syncthreads();  // (B) exch ready
    if (g == 1) {
#pragma unroll
      for (int r = 0; r < 4; ++r) {
        float rr = exch[jh][0][(lk * 4 + r) * 17 + lj];
        float np = exch[jh][1][(lk * 4 + r) * 17 + lj];
        float n = tanhf_(nxv[r] + rr * np);
        float hn = (1.f - zv[r]) * n + zv[r] * hown[r];
        hown[r] = hn;
        hout[lk * 4 + r][jh * 16 + lj] = (_Float16)hn;
      }
    }
    __syncthreads();  // (C) hout ready (implies vmcnt+lgkm drain per wave)
    if (wv == 0) {
      // coalesced fabric-coherent h16 store + plain hs16 store, then flag
      int row = lane >> 2, c = lane & 3;
      uint4v hv = *(const uint4v*)((const char*)hout + row * 64 + c * 16);
      char* p1 = (char*)(h16 + (size_t)(cur ^ 1) * (128 * 1024) +
                         (size_t)(b0 + row) * 1024 + js * 32 + c * 8);
      asm volatile("global_store_dwordx4 %0, %1, off sc0 sc1"
                   :: "v"(p1), "v"(hv) : "memory");
      _Float16* p2 = hs16 + ((size_t)t * 128 + b0 + row) * 1024 + js * 32 + c * 8;
      *(uint4v*)p2 = hv;
      asm volatile("s_waitcnt vmcnt(0)" ::: "memory");
      if (lane == 0) {
        int* fp = flags + ((size_t)bg * 32 + js) * 32;
        int val = gs + 1;
        asm volatile("global_store_dword %0, %1, off sc0 sc1"
                     :: "v"(fp), "v"(val) : "memory");
      }
    } else if (wv == 5) {
      // poll all 32 flags of this bgroup (lanes 32-63 mirror lanes 0-31)
      const int* fp = flags + ((size_t)bg * 32 + (lane & 31)) * 32;
      const int target = gs + 1;
      int spin = 0;
      while (true) {
        int v;
        asm volatile("global_load_dword %0, %1, off sc0 sc1\n\ts_waitcnt vmcnt(0)"
                     : "=v"(v) : "v"(fp) : "memory");
        if (__all(v >= target)) break;
        __builtin_amdgcn_s_sleep(1);
        if (++spin > (1 << 17)) break;  // safety valve vs hang
      }
    }
    __syncthreads();  // (D) all 32 blocks of bgroup have published h_{t+1}
    cur ^= 1;
  }
  if (g == 1) {
#pragma unroll
    for (int r = 0; r < 4; ++r) h32[(size_t)(b0 + lk * 4 + r) * 1024 + jcol] = hown[r];
  }
}

// ---------------- LayerNorm(hs + skip) -> fp16 ----------------
__global__ __launch_bounds__(256) void ln_kernel(
    const _Float16* __restrict__ hs, const _Float16* __restrict__ rz,
    const float* __restrict__ gamma, const float* __restrict__ beta,
    _Float16* __restrict__ outp) {
  const int row = blockIdx.x, tid = threadIdx.x;
  const int lane = tid & 63, wv = tid >> 6;
  half4v hv = *(const half4v*)(hs + (size_t)row * 1024 + tid * 4);
  half4v sv = *(const half4v*)(rz + (size_t)row * 4096 + 3072 + tid * 4);
  float v[4];
  float s = 0.f, s2 = 0.f;
#pragma unroll
  for (int j = 0; j < 4; ++j) {
    v[j] = (float)hv[j] + (float)sv[j];
    s += v[j];
    s2 += v[j] * v[j];
  }
#pragma unroll
  for (int o = 32; o > 0; o >>= 1) {
    s += __shfl_xor(s, o, 64);
    s2 += __shfl_xor(s2, o, 64);
  }
  __shared__ float ps[4][2];
  if (lane == 0) { ps[wv][0] = s; ps[wv][1] = s2; }
  __syncthreads();
  s = ps[0][0] + ps[1][0] + ps[2][0] + ps[3][0];
  s2 = ps[0][1] + ps[1][1] + ps[2][1] + ps[3][1];
  const float mu = s * (1.f / 1024.f);
  const float var = s2 * (1.f / 1024.f) - mu * mu;
  const float rstd = rsqrtf(var + 1e-5f);
  half4v ov;
#pragma unroll
  for (int j = 0; j < 4; ++j)
    ov[j] = (_Float16)((v[j] - mu) * rstd * gamma[tid * 4 + j] + beta[tid * 4 + j]);
  *(half4v*)(outp + (size_t)row * 1024 + tid * 4) = ov;
}

// ---------------- host ----------------
extern "C" void kernel_launch(void* const* d_in, const int* in_sizes, int n_in,
                              void* d_out, int out_size, void* d_ws, size_t ws_size,
                              hipStream_t stream) {
  const float* x     = (const float*)d_in[0];
  const float* Wir   = (const float*)d_in[1];
  const float* bir   = (const float*)d_in[2];
  const float* Whr   = (const float*)d_in[3];
  const float* bhr   = (const float*)d_in[4];
  const float* Wiz   = (const float*)d_in[5];
  const float* biz   = (const float*)d_in[6];
  const float* Whz   = (const float*)d_in[7];
  const float* bhz   = (const float*)d_in[8];
  const float* Win   = (const float*)d_in[9];
  const float* bin_  = (const float*)d_in[10];
  const float* Whn   = (const float*)d_in[11];
  const float* bhn   = (const float*)d_in[12];
  const float* Wskip = (const float*)d_in[13];
  const float* bskip = (const float*)d_in[14];
  const float* gamma = (const float*)d_in[15];
  const float* beta  = (const float*)d_in[16];
  const float* Wout  = (const float*)d_in[17];
  const float* bout  = (const float*)d_in[18];
  float* out = (float*)d_out;

  char* ws = (char*)d_ws;
  size_t off = 0;
  auto alloc = [&](size_t bytes) -> char* {
    char* p = ws + off;
    off += (bytes + 255) & ~(size_t)255;
    return p;
  };
  _Float16* x16    = (_Float16*)alloc((size_t)TC * 128 * 512 * 2);
  _Float16* Wcat   = (_Float16*)alloc((size_t)4096 * 512 * 2);
  _Float16* Whcat  = (_Float16*)alloc((size_t)3072 * 1024 * 2);
  _Float16* Wout16 = (_Float16*)alloc((size_t)512 * 1024 * 2);
  float*    bcat   = (float*)alloc(4096 * 4);
  _Float16* rznx   = (_Float16*)alloc((size_t)TC * 128 * 4096 * 2);
  _Float16* h16    = (_Float16*)alloc((size_t)2 * 128 * 1024 * 2);
  float*    h32    = (float*)alloc((size_t)128 * 1024 * 4);
  _Float16* hs16   = (_Float16*)alloc((size_t)TC * 128 * 1024 * 2);
  _Float16* normed = (_Float16*)alloc((size_t)TC * 128 * 1024 * 2);
  int*      flags  = (int*)alloc(8 * 32 * 32 * sizeof(int));  // 128B-padded flags

  k_cvt<<<512, 256, 0, stream>>>(Wir, Wcat + 0 * 524288, 131072);
  k_cvt<<<512, 256, 0, stream>>>(Wiz, Wcat + 1 * 524288, 131072);
  k_cvt<<<512, 256, 0, stream>>>(Win, Wcat + 2 * 524288, 131072);
  k_cvt<<<512, 256, 0, stream>>>(Wskip, Wcat + 3 * 524288, 131072);
  k_cvt<<<1024, 256, 0, stream>>>(Whr, Whcat + 0 * 1048576, 262144);
  k_cvt<<<1024, 256, 0, stream>>>(Whz, Whcat + 1 * 1048576, 262144);
  k_cvt<<<1024, 256, 0, stream>>>(Whn, Whcat + 2 * 1048576, 262144);
  k_cvt<<<512, 256, 0, stream>>>(Wout, Wout16, 131072);
  build_bcat<<<16, 256, 0, stream>>>(bir, biz, bin_, bskip, bcat);
  hipMemsetAsync(h16, 0, (size_t)2 * 128 * 1024 * 2, stream);
  hipMemsetAsync(h32, 0, (size_t)128 * 1024 * 4, stream);
  hipMemsetAsync(flags, 0, 8 * 32 * 32 * sizeof(int), stream);

  for (int c = 0; c < NCHUNK; ++c) {
    int t0 = c * TC;
    k_cvt_x<<<(TC * 128 * 512 / 4) / 256, 256, 0, stream>>>(x, x16, t0);
    gemm_f16<0><<<dim3(4096 / 128, TC * 128 / 128), 256, 0, stream>>>(
        x16, Wcat, bcat, rznx, nullptr, TC * 128, 4096, 512, 0);
    scan_kernel<<<256, 384, 0, stream>>>(rznx, Whcat, bhr, bhz, bhn, h16, h32, hs16, flags, c);
    ln_kernel<<<TC * 128, 256, 0, stream>>>(hs16, rznx, gamma, beta, normed);
    gemm_f16<1><<<dim3(512 / 128, TC * 128 / 128), 256, 0, stream>>>(
        normed, Wout16, bout, nullptr, out, TC * 128, 512, 1024, t0);
  }
}